// Round 3
// baseline (679.646 us; speedup 1.0000x reference)
//
#include <hip/hip_runtime.h>
#include <hip/hip_bf16.h>
#include <cstdint>

#define B_N 16384
#define KN 64
#define DN 256
#define AN 64

// pack two f32 -> one u32 of 2x bf16 (RTN); .x lands in low 16 bits
static __device__ inline unsigned int pk2(float a, float b) {
    __hip_bfloat162 h = __float22bfloat162_rn(make_float2(a, b));
    return *reinterpret_cast<unsigned int*>(&h);
}
static __device__ inline float bf_lo(unsigned int v) { return __uint_as_float(v << 16); }
static __device__ inline float bf_hi(unsigned int v) { return __uint_as_float(v & 0xFFFF0000u); }

// ---------------------------------------------------------------------------
// K0: M = Wq^T @ Wk  (256x256)  and  WgT = transpose(Wgate) (512x256)
// ---------------------------------------------------------------------------
__global__ __launch_bounds__(256) void prep_kernel(const float* __restrict__ Wq,
                                                   const float* __restrict__ Wk,
                                                   const float* __restrict__ Wgate,
                                                   float* __restrict__ M,
                                                   float* __restrict__ WgT) {
    int blk = blockIdx.x;
    int t = threadIdx.x;
    if (blk < DN) {
        float acc = 0.f;
        #pragma unroll
        for (int a = 0; a < AN; ++a)
            acc += Wq[a * DN + blk] * Wk[a * DN + t];
        M[blk * DN + t] = acc;
    } else {
        int k = blk - DN;                    // 0..511
        WgT[k * DN + t] = Wgate[t * (2 * DN) + k];
    }
}

// ---------------------------------------------------------------------------
// K1 (persistent, fully fused): each block owns 32 rows = 2 groups of 16.
// Per group: center+ppi -> LDS; qk = center @ M (M L2-resident);
// 16 neigh tiles (bf16 in LDS, reg-staged next-tile prefetch);
// per tile: logits -> softmax -> ppi renorm -> ctx -> sctx;
// then gate GEMM (WgT L2-resident) + sigmoid blend + store out.
// qk/gate VALU hides under the neigh HBM stream.
// ---------------------------------------------------------------------------
__global__ __launch_bounds__(256) void fused_kernel(const float* __restrict__ neigh,
                                                    const float* __restrict__ center,
                                                    const float* __restrict__ ppi,
                                                    const float* __restrict__ M,
                                                    const float* __restrict__ WgT,
                                                    const float* __restrict__ bgate,
                                                    float* __restrict__ out) {
    __shared__ unsigned int sn[KN * 128];     // 32 KB  current neigh tile (bf16 pairs)
    __shared__ float scen[16 * DN];           // 16 KB  group center rows (f32)
    __shared__ unsigned int sqk[16 * 128];    //  8 KB  group qk rows (bf16 pairs)
    __shared__ float sctx[16 * DN];           // 16 KB  group context rows (f32)
    __shared__ float sppi[16 * KN];           //  4 KB
    __shared__ float slog[KN];
    __shared__ float sattn[KN];
    __shared__ float scr[DN];                 //  1 KB  ctx k-half combine
    // total ~77.5 KB -> 2 blocks/CU

    const int tid = threadIdx.x;
    const int b_base = blockIdx.x * 32;

    // stage the very first tile into registers
    float4 rr[16];
    {
        const float4* t4 = (const float4*)(neigh + (size_t)b_base * (KN * DN));
        #pragma unroll
        for (int i = 0; i < 16; ++i) rr[i] = t4[tid + 256 * i];
    }

    for (int grp = 0; grp < 2; ++grp) {
        const int g0 = b_base + grp * 16;
        __syncthreads();                      // scen/sctx reuse vs previous gate reads

        // ---- group center + ppi -> LDS ----
        {
            const float4* c4 = (const float4*)(center + (size_t)g0 * DN);
            #pragma unroll
            for (int i = 0; i < 4; ++i)
                ((float4*)scen)[tid + 256 * i] = c4[tid + 256 * i];
            ((float4*)sppi)[tid] = ((const float4*)(ppi + (size_t)g0 * KN))[tid];
        }
        __syncthreads();

        // ---- qk GEMM: sqk[r][:] = bf16(scen[r] @ M), 16x256 ----
        {
            const int ty = tid >> 5, tx = tid & 31;
            float acc[2][8];
            #pragma unroll
            for (int r = 0; r < 2; ++r)
                #pragma unroll
                for (int c = 0; c < 8; ++c) acc[r][c] = 0.f;
            for (int k = 0; k < DN; k += 4) {
                float4 x0 = *(const float4*)&scen[(ty * 2 + 0) * DN + k];
                float4 x1 = *(const float4*)&scen[(ty * 2 + 1) * DN + k];
                #pragma unroll
                for (int kk = 0; kk < 4; ++kk) {
                    float4 ma = *(const float4*)&M[(size_t)(k + kk) * DN + tx * 8];
                    float4 mb = *(const float4*)&M[(size_t)(k + kk) * DN + tx * 8 + 4];
                    float xa = (&x0.x)[kk], xb = (&x1.x)[kk];
                    acc[0][0] += xa * ma.x; acc[0][1] += xa * ma.y;
                    acc[0][2] += xa * ma.z; acc[0][3] += xa * ma.w;
                    acc[0][4] += xa * mb.x; acc[0][5] += xa * mb.y;
                    acc[0][6] += xa * mb.z; acc[0][7] += xa * mb.w;
                    acc[1][0] += xb * ma.x; acc[1][1] += xb * ma.y;
                    acc[1][2] += xb * ma.z; acc[1][3] += xb * ma.w;
                    acc[1][4] += xb * mb.x; acc[1][5] += xb * mb.y;
                    acc[1][6] += xb * mb.z; acc[1][7] += xb * mb.w;
                }
            }
            #pragma unroll
            for (int r = 0; r < 2; ++r)
                #pragma unroll
                for (int c = 0; c < 4; ++c)
                    sqk[(ty * 2 + r) * 128 + tx * 4 + c] = pk2(acc[r][2 * c], acc[r][2 * c + 1]);
        }
        __syncthreads();

        // ---- 16 neigh tiles ----
        for (int ib = 0; ib < 16; ++ib) {
            const int b = g0 + ib;
            // staged regs -> LDS tile (bf16 pairs)
            {
                uint2* dst = (uint2*)sn;
                #pragma unroll
                for (int i = 0; i < 16; ++i)
                    dst[tid + 256 * i] = make_uint2(pk2(rr[i].x, rr[i].y), pk2(rr[i].z, rr[i].w));
            }
            // issue next-tile loads (T14: in flight during this tile's compute)
            {
                int nb = b + 1; if (nb >= B_N) nb = B_N - 1;
                const float4* t4 = (const float4*)(neigh + (size_t)nb * (KN * DN));
                #pragma unroll
                for (int i = 0; i < 16; ++i) rr[i] = t4[tid + 256 * i];
            }
            __syncthreads();                  // tile visible

            // logits: group g=tid>>2 owns k-row g; rotated d-walk (2-way banks, free)
            {
                const int g = tid >> 2, j = tid & 3;
                float acc = 0.f;
                #pragma unroll
                for (int m = 0; m < 32; ++m) {
                    int s = (m + g) & 31;
                    int p = j + 4 * s;        // pair index 0..127
                    unsigned int nv = sn[g * 128 + p];
                    unsigned int qv = sqk[ib * 128 + p];
                    acc += bf_lo(nv) * bf_lo(qv) + bf_hi(nv) * bf_hi(qv);
                }
                acc += __shfl_xor(acc, 1, 64);
                acc += __shfl_xor(acc, 2, 64);
                if (j == 0) slog[g] = acc;
            }
            __syncthreads();

            // softmax + ppi renorm (wave 0, exact reference semantics)
            if (tid < KN) {
                float l = slog[tid] * 0.125f; // scale = 64^-0.5
                float mx = l;
                #pragma unroll
                for (int off = 32; off >= 1; off >>= 1)
                    mx = fmaxf(mx, __shfl_xor(mx, off, 64));
                float e = expf(l - mx);
                float se = e;
                #pragma unroll
                for (int off = 32; off >= 1; off >>= 1)
                    se += __shfl_xor(se, off, 64);
                float pr = e / se;
                float t = pr * sppi[ib * KN + tid];
                float st = t;
                #pragma unroll
                for (int off = 32; off >= 1; off >>= 1)
                    st += __shfl_xor(st, off, 64);
                sattn[tid] = t / (st + 1e-8f);
            }
            __syncthreads();

            // context -> sctx[ib]
            {
                const int p = tid & 127, h = tid >> 7;
                float c0 = 0.f, c1 = 0.f;
                #pragma unroll
                for (int kk = 0; kk < 32; ++kk) {
                    int k = h * 32 + kk;
                    unsigned int nv = sn[k * 128 + p];
                    float a = sattn[k];
                    c0 += a * bf_lo(nv);
                    c1 += a * bf_hi(nv);
                }
                if (h == 1) ((float2*)scr)[p] = make_float2(c0, c1);
                __syncthreads();
                if (h == 0) {
                    float2 o = ((float2*)scr)[p];
                    ((float2*)&sctx[ib * DN])[p] = make_float2(o.x + c0, o.y + c1);
                }
            }
        }
        __syncthreads();                      // sctx complete

        // ---- gate GEMM + sigmoid blend + store ----
        {
            const int ty = tid >> 5, tx = tid & 31;
            float acc[2][8];
            #pragma unroll
            for (int r = 0; r < 2; ++r)
                #pragma unroll
                for (int c = 0; c < 8; ++c) acc[r][c] = 0.f;
            // first half: center columns (k = 0..255)
            for (int k = 0; k < DN; k += 4) {
                float4 x0 = *(const float4*)&scen[(ty * 2 + 0) * DN + k];
                float4 x1 = *(const float4*)&scen[(ty * 2 + 1) * DN + k];
                #pragma unroll
                for (int kk = 0; kk < 4; ++kk) {
                    float4 wa = *(const float4*)&WgT[(size_t)(k + kk) * DN + tx * 8];
                    float4 wb = *(const float4*)&WgT[(size_t)(k + kk) * DN + tx * 8 + 4];
                    float xa = (&x0.x)[kk], xb = (&x1.x)[kk];
                    acc[0][0] += xa * wa.x; acc[0][1] += xa * wa.y;
                    acc[0][2] += xa * wa.z; acc[0][3] += xa * wa.w;
                    acc[0][4] += xa * wb.x; acc[0][5] += xa * wb.y;
                    acc[0][6] += xa * wb.z; acc[0][7] += xa * wb.w;
                    acc[1][0] += xb * wa.x; acc[1][1] += xb * wa.y;
                    acc[1][2] += xb * wa.z; acc[1][3] += xb * wa.w;
                    acc[1][4] += xb * wb.x; acc[1][5] += xb * wb.y;
                    acc[1][6] += xb * wb.z; acc[1][7] += xb * wb.w;
                }
            }
            // second half: context columns (k = 256..511)
            for (int k = 0; k < DN; k += 4) {
                float4 x0 = *(const float4*)&sctx[(ty * 2 + 0) * DN + k];
                float4 x1 = *(const float4*)&sctx[(ty * 2 + 1) * DN + k];
                #pragma unroll
                for (int kk = 0; kk < 4; ++kk) {
                    float4 wa = *(const float4*)&WgT[(size_t)(DN + k + kk) * DN + tx * 8];
                    float4 wb = *(const float4*)&WgT[(size_t)(DN + k + kk) * DN + tx * 8 + 4];
                    float xa = (&x0.x)[kk], xb = (&x1.x)[kk];
                    acc[0][0] += xa * wa.x; acc[0][1] += xa * wa.y;
                    acc[0][2] += xa * wa.z; acc[0][3] += xa * wa.w;
                    acc[0][4] += xa * wb.x; acc[0][5] += xa * wb.y;
                    acc[0][6] += xa * wb.z; acc[0][7] += xa * wb.w;
                    acc[1][0] += xb * wa.x; acc[1][1] += xb * wa.y;
                    acc[1][2] += xb * wa.z; acc[1][3] += xb * wa.w;
                    acc[1][4] += xb * wb.x; acc[1][5] += xb * wb.y;
                    acc[1][6] += xb * wb.z; acc[1][7] += xb * wb.w;
                }
            }
            float4 bg0 = *(const float4*)&bgate[tx * 8];
            float4 bg1 = *(const float4*)&bgate[tx * 8 + 4];
            #pragma unroll
            for (int r = 0; r < 2; ++r) {
                int rl = ty * 2 + r;
                size_t row = (size_t)(g0 + rl);
                float o[8];
                #pragma unroll
                for (int c = 0; c < 8; ++c) {
                    float z = acc[r][c] + ((c < 4) ? (&bg0.x)[c] : (&bg1.x)[c - 4]);
                    float gt = 1.0f / (1.0f + expf(-z));
                    float ce = scen[rl * DN + tx * 8 + c];
                    float cx = sctx[rl * DN + tx * 8 + c];
                    o[c] = gt * ce + (1.0f - gt) * cx;
                }
                *(float4*)&out[row * DN + tx * 8]     = make_float4(o[0], o[1], o[2], o[3]);
                *(float4*)&out[row * DN + tx * 8 + 4] = make_float4(o[4], o[5], o[6], o[7]);
            }
        }
    }
}

// ---------------------------------------------------------------------------
extern "C" void kernel_launch(void* const* d_in, const int* in_sizes, int n_in,
                              void* d_out, int out_size, void* d_ws, size_t ws_size,
                              hipStream_t stream) {
    const float* center = (const float*)d_in[0];
    const float* neigh  = (const float*)d_in[1];
    const float* ppi    = (const float*)d_in[2];
    const float* Wq     = (const float*)d_in[3];
    const float* Wk     = (const float*)d_in[4];
    const float* Wgate  = (const float*)d_in[5];
    const float* bgate  = (const float*)d_in[6];
    float* out = (float*)d_out;

    char* ws = (char*)d_ws;
    float* M   = (float*)(ws);                                   // 256 KB
    float* WgT = (float*)(ws + 262144);                          // 512 KB

    prep_kernel<<<dim3(768), dim3(256), 0, stream>>>(Wq, Wk, Wgate, M, WgT);
    fused_kernel<<<dim3(B_N / 32), dim3(256), 0, stream>>>(neigh, center, ppi, M, WgT, bgate, out);
}